// Round 12
// baseline (2122.389 us; speedup 1.0000x reference)
//
#include <hip/hip_runtime.h>

#define NN     50000
#define NN_PAD 50048
#define NE     800000
#define INCH   8
#define CH     128
#define EA     6
#define NB     2000
#define NCLS   32
#define FUS    384

typedef _Float16 half8 __attribute__((ext_vector_type(8)));
typedef float f32x4 __attribute__((ext_vector_type(4)));

// ---------- degree of dst nodes ----------
__global__ __launch_bounds__(256) void k_deg(const int* __restrict__ edge,
                                             int* __restrict__ deg) {
  int e = blockIdx.x * 256 + threadIdx.x;
  if (e < NE) atomicAdd(&deg[edge[NE + e]], 1);
}

// ---------- exclusive scan of deg -> row_ptr (single block, shfl scan) ----------
__global__ __launch_bounds__(1024) void k_scan(const int* __restrict__ deg,
                                               int* __restrict__ row_ptr) {
  __shared__ int wsum[16];
  __shared__ int s_carry;
  const int t = threadIdx.x, lane = t & 63, w = t >> 6;
  if (t == 0) s_carry = 0;
  __syncthreads();
  for (int base = 0; base < NN; base += 1024) {
    int i = base + t;
    int x = (i < NN) ? deg[i] : 0;
#pragma unroll
    for (int off = 1; off < 64; off <<= 1) {
      int y = __shfl_up(x, off, 64);
      if (lane >= off) x += y;
    }
    if (lane == 63) wsum[w] = x;
    __syncthreads();
    if (w == 0 && lane < 16) {
      int s = wsum[lane];
#pragma unroll
      for (int off = 1; off < 16; off <<= 1) {
        int y = __shfl_up(s, off, 64);
        if (lane >= off) s += y;
      }
      wsum[lane] = s;
    }
    __syncthreads();
    int incl = x + ((w == 0) ? 0 : wsum[w - 1]) + s_carry;
    if (i < NN) row_ptr[i + 1] = incl;
    __syncthreads();
    if (t == 1023) s_carry = incl;
    __syncthreads();
  }
  if (t == 0) row_ptr[0] = 0;
}

// ---------- fill CSR: edge ids grouped by dst ----------
__global__ __launch_bounds__(256) void k_fill(
    const int* __restrict__ edge, const int* __restrict__ row_ptr,
    int* __restrict__ cursor, int* __restrict__ eid_arr) {
  int e = blockIdx.x * 256 + threadIdx.x;
  if (e >= NE) return;
  int d = edge[NE + e];
  int idx = row_ptr[d] + atomicAdd(&cursor[d], 1);
  eid_arr[idx] = e;
}

// ---------- segment starts from sorted bbox_idx ----------
__global__ __launch_bounds__(256) void k_segstart(const int* __restrict__ bbox,
                                                  int* __restrict__ seg) {
  int i = blockIdx.x * 256 + threadIdx.x;
  if (i >= NN) return;
  int bc = bbox[i];
  int bp = (i == 0) ? -1 : bbox[i - 1];
  for (int j = bp + 1; j <= bc; ++j) seg[j] = i;
  if (i == NN - 1)
    for (int j = bc + 1; j <= NB; ++j) seg[j] = NN;
}

// ---------- node transform: P = X@(W1-W2)+b, Q = X@W2 ----------
__global__ __launch_bounds__(256) void k_node_pq(
    const float* __restrict__ X, int ldx, int K,
    const float* __restrict__ W, const float* __restrict__ bias,
    float* __restrict__ P, float* __restrict__ Q) {
  const int t = threadIdx.x, lane = t & 63, wv = t >> 6;
  const int nbase = blockIdx.x * 32 + wv * 8;
  const int c = lane * 2;
  const float2 bv = *(const float2*)(bias + c);
  float2 pacc[8], qacc[8];
#pragma unroll
  for (int u = 0; u < 8; ++u) { pacc[u] = bv; qacc[u] = make_float2(0.f, 0.f); }
  const int xrow = min(nbase + (lane >> 3), NN - 1);
  const int xk = lane & 7;
  for (int k0 = 0; k0 < K; k0 += 8) {
    const float xv = X[(size_t)xrow * ldx + k0 + xk];
#pragma unroll
    for (int j = 0; j < 8; ++j) {
      const float2 w1 = *(const float2*)(W + (size_t)(k0 + j) * CH + c);
      const float2 w2 = *(const float2*)(W + (size_t)(K + k0 + j) * CH + c);
      const float2 wd = {w1.x - w2.x, w1.y - w2.y};
#pragma unroll
      for (int u = 0; u < 8; ++u) {
        const float xs = __shfl(xv, u * 8 + j, 64);
        pacc[u].x += xs * wd.x; pacc[u].y += xs * wd.y;
        qacc[u].x += xs * w2.x; qacc[u].y += xs * w2.y;
      }
    }
  }
#pragma unroll
  for (int u = 0; u < 8; ++u) {
    const int node = nbase + u;
    if (node < NN) {
      *(float2*)(P + (size_t)node * CH + c) = pacc[u];
      *(float2*)(Q + (size_t)node * CH + c) = qacc[u];
    }
  }
}

// ---------- CSR conv: one node per WAVE, lane-batched edge meta + shfl ----------
template <int MODE>  // 0 = max, 1 = mean
__global__ __launch_bounds__(256) void k_conv(
    const int* __restrict__ row_ptr, const int* __restrict__ eid_arr,
    const int* __restrict__ edge, const float* __restrict__ eattr,
    const float* __restrict__ P, const float* __restrict__ Q,
    const float* __restrict__ C, float* __restrict__ outf,
    int cur, int prev) {
  const int t = threadIdx.x;
  const int lane = t & 63;
  const int node = blockIdx.x * 4 + (t >> 6);
  const int c = lane * 2;
  float2 cw[EA];
#pragma unroll
  for (int j = 0; j < EA; ++j) cw[j] = *(const float2*)(C + j * CH + c);
  int i0 = __builtin_amdgcn_readfirstlane(row_ptr[node]);
  int i1 = __builtin_amdgcn_readfirstlane(row_ptr[node + 1]);
  const float2 q = *(const float2*)(Q + (size_t)node * CH + c);
  float a0 = 0.f, a1 = 0.f;
  for (int base = i0; base < i1; base += 64) {
    const int cnt = min(64, i1 - base);
    int s_l = 0;
    float ea0 = 0.f, ea1 = 0.f, ea2 = 0.f, ea3 = 0.f, ea4 = 0.f, ea5 = 0.f;
    if (lane < cnt) {
      int e = eid_arr[base + lane];      // coalesced
      s_l = edge[e];                     // gather
      const float* ep = eattr + (size_t)e * EA;
      ea0 = ep[0]; ea1 = ep[1]; ea2 = ep[2];
      ea3 = ep[3]; ea4 = ep[4]; ea5 = ep[5];
    }
#define EDGE_BODY(J)                                                       \
    {                                                                      \
      int s = __shfl(s_l, (J), 64);                                        \
      float e0 = __shfl(ea0, (J), 64), e1 = __shfl(ea1, (J), 64);          \
      float e2 = __shfl(ea2, (J), 64), e3 = __shfl(ea3, (J), 64);          \
      float e4 = __shfl(ea4, (J), 64), e5 = __shfl(ea5, (J), 64);          \
      const float2 pv = *(const float2*)(P + (size_t)s * CH + c);          \
      float v0 = pv.x + q.x, v1 = pv.y + q.y;                              \
      v0 += e0 * cw[0].x; v1 += e0 * cw[0].y;                              \
      v0 += e1 * cw[1].x; v1 += e1 * cw[1].y;                              \
      v0 += e2 * cw[2].x; v1 += e2 * cw[2].y;                              \
      v0 += e3 * cw[3].x; v1 += e3 * cw[3].y;                              \
      v0 += e4 * cw[4].x; v1 += e4 * cw[4].y;                              \
      v0 += e5 * cw[5].x; v1 += e5 * cw[5].y;                              \
      if (MODE == 0) { a0 = fmaxf(a0, v0); a1 = fmaxf(a1, v1); }           \
      else           { a0 += fmaxf(v0, 0.f); a1 += fmaxf(v1, 0.f); }       \
    }
    int j = 0;
    for (; j + 8 <= cnt; j += 8) {
      EDGE_BODY(j)     EDGE_BODY(j + 1) EDGE_BODY(j + 2) EDGE_BODY(j + 3)
      EDGE_BODY(j + 4) EDGE_BODY(j + 5) EDGE_BODY(j + 6) EDGE_BODY(j + 7)
    }
    for (; j < cnt; ++j) EDGE_BODY(j)
#undef EDGE_BODY
  }
  if (MODE == 1) {
    float inv = 1.f / fmaxf((float)(i1 - i0), 1.f);
    a0 *= inv; a1 *= inv;
  }
  size_t o = (size_t)node * FUS + (size_t)cur * CH + c;
  if (prev >= 0) {
    const float2 pr = *(const float2*)(outf + (size_t)node * FUS + (size_t)prev * CH + c);
    a0 += pr.x; a1 += pr.y;
  }
  float2 ov = {a0, a1};
  *(float2*)(outf + o) = ov;
}

// ---------- convert feats -> f16, rows >= NN zero-padded ----------
__global__ __launch_bounds__(256) void k_cvtA(const float* __restrict__ feats,
                                              _Float16* __restrict__ fh) {
  const size_t off = ((size_t)blockIdx.x * 256 + threadIdx.x) * 8;
  const int row = (int)(off / FUS);
  half8 v;
  if (row < NN) {
    const float4 f0 = *(const float4*)(feats + off);
    const float4 f1 = *(const float4*)(feats + off + 4);
    v[0] = (_Float16)f0.x; v[1] = (_Float16)f0.y;
    v[2] = (_Float16)f0.z; v[3] = (_Float16)f0.w;
    v[4] = (_Float16)f1.x; v[5] = (_Float16)f1.y;
    v[6] = (_Float16)f1.z; v[7] = (_Float16)f1.w;
  } else {
#pragma unroll
    for (int j = 0; j < 8; ++j) v[j] = (_Float16)0.f;
  }
  *(half8*)(fh + off) = v;
}

// ---------- convert + pack W_f into B-fragment order ----------
__global__ __launch_bounds__(64) void k_cvtB(const float* __restrict__ Wf,
                                             _Float16* __restrict__ wh) {
  const int c = blockIdx.x >> 6;      // 0..11
  const int tile = blockIdx.x & 63;   // 0..63
  const int L = threadIdx.x;
  const int n = tile * 16 + (L & 15);
  const int k0 = c * 32 + (L >> 4) * 8;
  half8 v;
#pragma unroll
  for (int j = 0; j < 8; ++j) v[j] = (_Float16)Wf[(size_t)(k0 + j) * 1024 + n];
  *(half8*)(wh + (((size_t)(c * 64 + tile)) * 64 + L) * 8) = v;
}

// ---------- fusion GEMM on matrix cores + segment max ----------
__global__ __launch_bounds__(256) void k_pool_mfma(
    const _Float16* __restrict__ fh, const _Float16* __restrict__ wh,
    const int* __restrict__ bbox, const float* __restrict__ bf,
    float* __restrict__ pooled) {
  __shared__ float cl[64 * 128];
  const int t = threadIdx.x, lane = t & 63, wv = t >> 6;
  const int nbase = blockIdx.x * 64;
  const int cg = blockIdx.y;          // column group of 128
  const int m = lane & 15, quad = lane >> 4;
  f32x4 acc[4][2];
#pragma unroll
  for (int i = 0; i < 4; ++i)
#pragma unroll
    for (int nt = 0; nt < 2; ++nt) acc[i][nt] = (f32x4){0.f, 0.f, 0.f, 0.f};
  const _Float16* ap = fh + (size_t)(nbase + m) * FUS + quad * 8;
  const _Float16* bp = wh + ((size_t)(cg * 8 + wv * 2) * 64 + lane) * 8;
#pragma unroll
  for (int ks = 0; ks < 12; ++ks) {
    const half8 b0 = *(const half8*)(bp + (size_t)ks * 32768);
    const half8 b1 = *(const half8*)(bp + (size_t)ks * 32768 + 512);
#pragma unroll
    for (int i = 0; i < 4; ++i) {
      const half8 a = *(const half8*)(ap + (size_t)(i * 16) * FUS + ks * 32);
      acc[i][0] = __builtin_amdgcn_mfma_f32_16x16x32_f16(a, b0, acc[i][0], 0, 0, 0);
      acc[i][1] = __builtin_amdgcn_mfma_f32_16x16x32_f16(a, b1, acc[i][1], 0, 0, 0);
    }
  }
#pragma unroll
  for (int i = 0; i < 4; ++i)
#pragma unroll
    for (int nt = 0; nt < 2; ++nt) {
      const int col = wv * 32 + nt * 16 + m;
#pragma unroll
      for (int r = 0; r < 4; ++r)
        cl[(i * 16 + quad * 4 + r) * 128 + col] = acc[i][nt][r];
    }
  __syncthreads();
  if (t < 128) {
    const int gcol = cg * 128 + t;
    const float bias = bf[gcol];
    int curb = -1;
    float mx = 0.f;
    for (int row = 0; row < 64; ++row) {
      const int node = nbase + row;
      if (node >= NN) break;
      const int bid = bbox[node];
      const float v = fmaxf(cl[row * 128 + t] + bias, 0.f);
      if (bid != curb) {
        if (curb >= 0)
          atomicMax((unsigned*)(pooled + (size_t)curb * 1408 + gcol),
                    __float_as_uint(mx));
        curb = bid;
        mx = v;
      } else {
        mx = fmaxf(mx, v);
      }
    }
    if (curb >= 0)
      atomicMax((unsigned*)(pooled + (size_t)curb * 1408 + gcol),
                __float_as_uint(mx));
  }
}

// ---------- raw-feats bbox max + sfeats bbox mean ----------
__global__ __launch_bounds__(256) void k_poolraw(
    const float* __restrict__ feats, const float* __restrict__ sfeats,
    const int* __restrict__ seg, float* __restrict__ pooled,
    float* __restrict__ sb) {
  const int b = blockIdx.x, t = threadIdx.x;
  if (t >= 192) return;
  const int c2 = t * 2;
  const int n0 = __builtin_amdgcn_readfirstlane(seg[b]);
  const int n1 = __builtin_amdgcn_readfirstlane(seg[b + 1]);
  float2 fmx = {0.f, 0.f}, ss = {0.f, 0.f};
  for (int n = n0; n < n1; ++n) {
    const float2 f2 = *(const float2*)(feats + (size_t)n * FUS + c2);
    fmx.x = fmaxf(fmx.x, f2.x); fmx.y = fmaxf(fmx.y, f2.y);
    const float2 s2 = *(const float2*)(sfeats + (size_t)n * FUS + c2);
    ss.x += s2.x; ss.y += s2.y;
  }
  *(float2*)(pooled + (size_t)b * 1408 + 1024 + c2) = fmx;
  const float inv = 1.f / fmaxf((float)(n1 - n0), 1.f);
  float2 o = {ss.x * inv, ss.y * inv};
  *(float2*)(sb + (size_t)b * FUS + c2) = o;
}

// ---------- fusion_super = relu(sb @ Wfs + bfs), lane-distributed x ----------
// Wave: 4 rows x 128 cols (2 cols/lane). x: lane>>4 = row, lane&15 = k;
// consumed via static shfl. Grid (500, 2); block 4 waves = col groups.
__global__ __launch_bounds__(256) void k_fusion_super(
    const float* __restrict__ sb, const float* __restrict__ Wfs,
    const float* __restrict__ bfs, float* __restrict__ fs) {
  const int t = threadIdx.x, lane = t & 63, wv = t >> 6;
  const int r0 = blockIdx.x * 4;
  const int c = (blockIdx.y * 4 + wv) * 128 + lane * 2;
  float2 acc[4];
#pragma unroll
  for (int u = 0; u < 4; ++u) acc[u] = make_float2(0.f, 0.f);
  const int xr = r0 + (lane >> 4), xk = lane & 15;
  for (int k0 = 0; k0 < FUS; k0 += 16) {
    const float xv = sb[(size_t)xr * FUS + k0 + xk];
#pragma unroll
    for (int j = 0; j < 16; ++j) {
      const float2 w = *(const float2*)(Wfs + (size_t)(k0 + j) * 1024 + c);
#pragma unroll
      for (int u = 0; u < 4; ++u) {
        const float xs = __shfl(xv, u * 16 + j, 64);
        acc[u].x += xs * w.x; acc[u].y += xs * w.y;
      }
    }
  }
  const float2 b = *(const float2*)(bfs + c);
#pragma unroll
  for (int u = 0; u < 4; ++u) {
    float2 o = {fmaxf(acc[u].x + b.x, 0.f), fmaxf(acc[u].y + b.y, 0.f)};
    *(float2*)(fs + (size_t)(r0 + u) * 1024 + c) = o;
  }
}

// ---------- h1 = relu(concat(pooled, fs, sb) @ W1 + b1), lane-distributed x ----
// Wave: 4 rows x 128 cols (2 cols/lane); 3 K-segments (1408/1024/384, all %16).
// Grid 500; block 4 waves = 4 col groups (512 cols).
__global__ __launch_bounds__(256) void k_mlp1(
    const float* __restrict__ pooled, const float* __restrict__ fs,
    const float* __restrict__ sb, const float* __restrict__ W1,
    const float* __restrict__ b1, float* __restrict__ h1) {
  const int t = threadIdx.x, lane = t & 63, wv = t >> 6;
  const int r0 = blockIdx.x * 4;
  const int c = wv * 128 + lane * 2;
  float2 acc[4];
#pragma unroll
  for (int u = 0; u < 4; ++u) acc[u] = make_float2(0.f, 0.f);
  const int xr = r0 + (lane >> 4), xk = lane & 15;
  for (int k0 = 0; k0 < 1408; k0 += 16) {
    const float xv = pooled[(size_t)xr * 1408 + k0 + xk];
#pragma unroll
    for (int j = 0; j < 16; ++j) {
      const float2 w = *(const float2*)(W1 + (size_t)(k0 + j) * 512 + c);
#pragma unroll
      for (int u = 0; u < 4; ++u) {
        const float xs = __shfl(xv, u * 16 + j, 64);
        acc[u].x += xs * w.x; acc[u].y += xs * w.y;
      }
    }
  }
  for (int k0 = 0; k0 < 1024; k0 += 16) {
    const float xv = fs[(size_t)xr * 1024 + k0 + xk];
#pragma unroll
    for (int j = 0; j < 16; ++j) {
      const float2 w = *(const float2*)(W1 + (size_t)(1408 + k0 + j) * 512 + c);
#pragma unroll
      for (int u = 0; u < 4; ++u) {
        const float xs = __shfl(xv, u * 16 + j, 64);
        acc[u].x += xs * w.x; acc[u].y += xs * w.y;
      }
    }
  }
  for (int k0 = 0; k0 < FUS; k0 += 16) {
    const float xv = sb[(size_t)xr * FUS + k0 + xk];
#pragma unroll
    for (int j = 0; j < 16; ++j) {
      const float2 w = *(const float2*)(W1 + (size_t)(2432 + k0 + j) * 512 + c);
#pragma unroll
      for (int u = 0; u < 4; ++u) {
        const float xs = __shfl(xv, u * 16 + j, 64);
        acc[u].x += xs * w.x; acc[u].y += xs * w.y;
      }
    }
  }
  const float2 b = *(const float2*)(b1 + c);
#pragma unroll
  for (int u = 0; u < 4; ++u) {
    float2 o = {fmaxf(acc[u].x + b.x, 0.f), fmaxf(acc[u].y + b.y, 0.f)};
    *(float2*)(h1 + (size_t)(r0 + u) * 512 + c) = o;
  }
}

// ---------- h2 = relu(h1 @ W2 + b2) ----------
__global__ __launch_bounds__(256) void k_mlp2(
    const float* __restrict__ h1, const float* __restrict__ W2,
    const float* __restrict__ b2, float* __restrict__ h2) {
  const int r0 = blockIdx.x * 8, t = threadIdx.x;
  float acc[8];
#pragma unroll
  for (int u = 0; u < 8; ++u) acc[u] = 0.f;
  for (int k = 0; k < 512; ++k) {
    float w = W2[(size_t)k * 256 + t];
#pragma unroll
    for (int u = 0; u < 8; ++u) acc[u] += h1[(size_t)(r0 + u) * 512 + k] * w;
  }
  float bv = b2[t];
#pragma unroll
  for (int u = 0; u < 8; ++u)
    h2[(size_t)(r0 + u) * 256 + t] = fmaxf(acc[u] + bv, 0.f);
}

// ---------- logits = h2 @ W3 + b3 ----------
__global__ __launch_bounds__(256) void k_mlp3(
    const float* __restrict__ h2, const float* __restrict__ W3,
    const float* __restrict__ b3, float* __restrict__ out) {
  const int r0 = blockIdx.x * 8, t = threadIdx.x;
  const int u = t >> 5, oc = t & 31;
  const float* x = h2 + (size_t)(r0 + u) * 256;
  float acc = 0.f;
  for (int k = 0; k < 256; ++k) acc += x[k] * W3[(size_t)k * 32 + oc];
  out[(size_t)(r0 + u) * 32 + oc] = acc + b3[oc];
}

extern "C" void kernel_launch(void* const* d_in, const int* in_sizes, int n_in,
                              void* d_out, int out_size, void* d_ws, size_t ws_size,
                              hipStream_t stream) {
  const float* x     = (const float*)d_in[0];
  const float* eattr = (const float*)d_in[1];
  const float* W_h   = (const float*)d_in[2];
  const float* b_h   = (const float*)d_in[3];
  const float* Ws_h  = (const float*)d_in[4];
  const float* bs_h  = (const float*)d_in[5];
  const float* Wb    = (const float*)d_in[6];
  const float* bb    = (const float*)d_in[7];
  const float* Wbs   = (const float*)d_in[8];
  const float* bbs   = (const float*)d_in[9];
  const float* W_f   = (const float*)d_in[10];
  const float* b_f   = (const float*)d_in[11];
  const float* W_fs  = (const float*)d_in[12];
  const float* b_fs  = (const float*)d_in[13];
  const float* W1    = (const float*)d_in[14];
  const float* b1    = (const float*)d_in[15];
  const float* W2    = (const float*)d_in[16];
  const float* b2    = (const float*)d_in[17];
  const float* W3    = (const float*)d_in[18];
  const float* b3    = (const float*)d_in[19];
  const int*   edge  = (const int*)d_in[20];
  const int*   bbox  = (const int*)d_in[21];
  float* out = (float*)d_out;

  // ---- workspace layout (~209 MB, unchanged footprint) ----
  float* p = (float*)d_ws;
  float* feats  = p; p += (size_t)NN * FUS;       // 76.8 MB
  float* sfeats = p; p += (size_t)NN * FUS;       // 76.8 MB
  float* PQ     = p; p += (size_t)2 * NN * CH;    // 51.2 MB = 12.8M floats
  float* P = PQ;
  float* Q = PQ + (size_t)NN * CH;
  // overlays inside PQ (live only AFTER the last k_conv):
  _Float16* featsH = (_Float16*)PQ;                         // 9.609M floats
  _Float16* WfH    = featsH + (size_t)NN_PAD * FUS;         // 0.197M floats
  float* pooled    = (float*)(WfH + (size_t)FUS * 1024);    // 2.816M floats
  //   total: 12.62M <= 12.8M floats. After k_pool_mfma, featsH region reused:
  float* sb   = PQ;                                         // 0.768M
  float* fsup = sb + (size_t)NB * FUS;                      // 2.048M
  float* h1   = fsup + (size_t)NB * 1024;                   // 1.024M
  float* h2   = h1 + (size_t)NB * 512;                      // 0.512M (4.35M <= 9.6M)
  int* eid_arr = (int*)p;
  int* row_ptr = eid_arr + NE;
  int* deg     = row_ptr + NN + 1;
  int* cursor  = deg + NN;
  int* seg     = cursor + NN;

  hipMemsetAsync(deg, 0, 2 * NN * sizeof(int), stream);  // deg + cursor

  // ---- CSR build + bbox segments ----
  k_deg<<<(NE + 255) / 256, 256, 0, stream>>>(edge, deg);
  k_scan<<<1, 1024, 0, stream>>>(deg, row_ptr);
  k_fill<<<(NE + 255) / 256, 256, 0, stream>>>(edge, row_ptr, cursor, eid_arr);
  k_segstart<<<(NN + 255) / 256, 256, 0, stream>>>(bbox, seg);

  const int npq_grid = (NN + 31) / 32;

  // ---- conv 0 (head): both streams read x (K=8) ----
  k_node_pq<<<npq_grid, 256, 0, stream>>>(x, INCH, INCH, W_h, b_h, P, Q);
  k_conv<0><<<NN / 4, 256, 0, stream>>>(row_ptr, eid_arr, edge, eattr, P, Q,
                                        W_h + 2 * INCH * CH, feats, 0, -1);
  k_node_pq<<<npq_grid, 256, 0, stream>>>(x, INCH, INCH, Ws_h, bs_h, P, Q);
  k_conv<1><<<NN / 4, 256, 0, stream>>>(row_ptr, eid_arr, edge, eattr, P, Q,
                                        Ws_h + 2 * INCH * CH, sfeats, 0, -1);

  // ---- residual blocks (K=128) ----
  for (int i = 0; i < 2; ++i) {
    const float* Wi  = Wb  + (size_t)i * 262 * CH;
    const float* bi  = bb  + (size_t)i * CH;
    const float* Wsi = Wbs + (size_t)i * 262 * CH;
    const float* bsi = bbs + (size_t)i * CH;
    k_node_pq<<<npq_grid, 256, 0, stream>>>(feats + i * CH, FUS, CH, Wi, bi, P, Q);
    k_conv<0><<<NN / 4, 256, 0, stream>>>(row_ptr, eid_arr, edge, eattr, P, Q,
                                          Wi + 2 * CH * CH, feats, i + 1, i);
    k_node_pq<<<npq_grid, 256, 0, stream>>>(sfeats + i * CH, FUS, CH, Wsi, bsi, P, Q);
    k_conv<1><<<NN / 4, 256, 0, stream>>>(row_ptr, eid_arr, edge, eattr, P, Q,
                                          Wsi + 2 * CH * CH, sfeats, i + 1, i);
  }

  // ---- pooling: f16 converts + MFMA GEMM + atomicMax epilogue ----
  k_cvtA<<<(int)(((size_t)NN_PAD * FUS / 8) / 256), 256, 0, stream>>>(feats, featsH);
  k_cvtB<<<12 * 64, 64, 0, stream>>>(W_f, WfH);
  hipMemsetAsync(pooled, 0, (size_t)NB * 1408 * sizeof(float), stream);
  k_pool_mfma<<<dim3(NN_PAD / 64, 8), 256, 0, stream>>>(featsH, WfH, bbox, b_f,
                                                        pooled);
  k_poolraw<<<NB, 256, 0, stream>>>(feats, sfeats, seg, pooled, sb);
  k_fusion_super<<<dim3(NB / 4, 2), 256, 0, stream>>>(sb, W_fs, b_fs, fsup);
  k_mlp1<<<NB / 4, 256, 0, stream>>>(pooled, fsup, sb, W1, b1, h1);
  k_mlp2<<<NB / 8, 256, 0, stream>>>(h1, W2, b2, h2);
  k_mlp3<<<NB / 8, 256, 0, stream>>>(h2, W3, b3, out);
}

// Round 13
// 1828.530 us; speedup vs baseline: 1.1607x; 1.1607x over previous
//
#include <hip/hip_runtime.h>

#define NN     50000
#define NN_PAD 50048
#define NE     800000
#define INCH   8
#define CH     128
#define EA     6
#define NB     2000
#define NB_PAD 2048
#define NCLS   32
#define FUS    384
#define K1     2816   // 1408 + 1024 + 384

typedef _Float16 half8 __attribute__((ext_vector_type(8)));
typedef float f32x4 __attribute__((ext_vector_type(4)));

// ---------- degree of dst nodes ----------
__global__ __launch_bounds__(256) void k_deg(const int* __restrict__ edge,
                                             int* __restrict__ deg) {
  int e = blockIdx.x * 256 + threadIdx.x;
  if (e < NE) atomicAdd(&deg[edge[NE + e]], 1);
}

// ---------- exclusive scan of deg -> row_ptr (single block, shfl scan) ----------
__global__ __launch_bounds__(1024) void k_scan(const int* __restrict__ deg,
                                               int* __restrict__ row_ptr) {
  __shared__ int wsum[16];
  __shared__ int s_carry;
  const int t = threadIdx.x, lane = t & 63, w = t >> 6;
  if (t == 0) s_carry = 0;
  __syncthreads();
  for (int base = 0; base < NN; base += 1024) {
    int i = base + t;
    int x = (i < NN) ? deg[i] : 0;
#pragma unroll
    for (int off = 1; off < 64; off <<= 1) {
      int y = __shfl_up(x, off, 64);
      if (lane >= off) x += y;
    }
    if (lane == 63) wsum[w] = x;
    __syncthreads();
    if (w == 0 && lane < 16) {
      int s = wsum[lane];
#pragma unroll
      for (int off = 1; off < 16; off <<= 1) {
        int y = __shfl_up(s, off, 64);
        if (lane >= off) s += y;
      }
      wsum[lane] = s;
    }
    __syncthreads();
    int incl = x + ((w == 0) ? 0 : wsum[w - 1]) + s_carry;
    if (i < NN) row_ptr[i + 1] = incl;
    __syncthreads();
    if (t == 1023) s_carry = incl;
    __syncthreads();
  }
  if (t == 0) row_ptr[0] = 0;
}

// ---------- fill CSR: edge ids grouped by dst ----------
__global__ __launch_bounds__(256) void k_fill(
    const int* __restrict__ edge, const int* __restrict__ row_ptr,
    int* __restrict__ cursor, int* __restrict__ eid_arr) {
  int e = blockIdx.x * 256 + threadIdx.x;
  if (e >= NE) return;
  int d = edge[NE + e];
  int idx = row_ptr[d] + atomicAdd(&cursor[d], 1);
  eid_arr[idx] = e;
}

// ---------- segment starts from sorted bbox_idx ----------
__global__ __launch_bounds__(256) void k_segstart(const int* __restrict__ bbox,
                                                  int* __restrict__ seg) {
  int i = blockIdx.x * 256 + threadIdx.x;
  if (i >= NN) return;
  int bc = bbox[i];
  int bp = (i == 0) ? -1 : bbox[i - 1];
  for (int j = bp + 1; j <= bc; ++j) seg[j] = i;
  if (i == NN - 1)
    for (int j = bc + 1; j <= NB; ++j) seg[j] = NN;
}

// ---------- node transform: P = X@(W1-W2)+b, Q = X@W2 ----------
__global__ __launch_bounds__(256) void k_node_pq(
    const float* __restrict__ X, int ldx, int K,
    const float* __restrict__ W, const float* __restrict__ bias,
    float* __restrict__ P, float* __restrict__ Q) {
  const int t = threadIdx.x, lane = t & 63, wv = t >> 6;
  const int nbase = blockIdx.x * 32 + wv * 8;
  const int c = lane * 2;
  const float2 bv = *(const float2*)(bias + c);
  float2 pacc[8], qacc[8];
#pragma unroll
  for (int u = 0; u < 8; ++u) { pacc[u] = bv; qacc[u] = make_float2(0.f, 0.f); }
  const int xrow = min(nbase + (lane >> 3), NN - 1);
  const int xk = lane & 7;
  for (int k0 = 0; k0 < K; k0 += 8) {
    const float xv = X[(size_t)xrow * ldx + k0 + xk];
#pragma unroll
    for (int j = 0; j < 8; ++j) {
      const float2 w1 = *(const float2*)(W + (size_t)(k0 + j) * CH + c);
      const float2 w2 = *(const float2*)(W + (size_t)(K + k0 + j) * CH + c);
      const float2 wd = {w1.x - w2.x, w1.y - w2.y};
#pragma unroll
      for (int u = 0; u < 8; ++u) {
        const float xs = __shfl(xv, u * 8 + j, 64);
        pacc[u].x += xs * wd.x; pacc[u].y += xs * wd.y;
        qacc[u].x += xs * w2.x; qacc[u].y += xs * w2.y;
      }
    }
  }
#pragma unroll
  for (int u = 0; u < 8; ++u) {
    const int node = nbase + u;
    if (node < NN) {
      *(float2*)(P + (size_t)node * CH + c) = pacc[u];
      *(float2*)(Q + (size_t)node * CH + c) = qacc[u];
    }
  }
}

// ---------- CSR conv: one node per WAVE, lane-batched edge meta + shfl ----------
template <int MODE>  // 0 = max, 1 = mean
__global__ __launch_bounds__(256) void k_conv(
    const int* __restrict__ row_ptr, const int* __restrict__ eid_arr,
    const int* __restrict__ edge, const float* __restrict__ eattr,
    const float* __restrict__ P, const float* __restrict__ Q,
    const float* __restrict__ C, float* __restrict__ outf,
    int cur, int prev) {
  const int t = threadIdx.x;
  const int lane = t & 63;
  const int node = blockIdx.x * 4 + (t >> 6);
  const int c = lane * 2;
  float2 cw[EA];
#pragma unroll
  for (int j = 0; j < EA; ++j) cw[j] = *(const float2*)(C + j * CH + c);
  int i0 = __builtin_amdgcn_readfirstlane(row_ptr[node]);
  int i1 = __builtin_amdgcn_readfirstlane(row_ptr[node + 1]);
  const float2 q = *(const float2*)(Q + (size_t)node * CH + c);
  float a0 = 0.f, a1 = 0.f;
  for (int base = i0; base < i1; base += 64) {
    const int cnt = min(64, i1 - base);
    int s_l = 0;
    float ea0 = 0.f, ea1 = 0.f, ea2 = 0.f, ea3 = 0.f, ea4 = 0.f, ea5 = 0.f;
    if (lane < cnt) {
      int e = eid_arr[base + lane];      // coalesced
      s_l = edge[e];                     // gather
      const float* ep = eattr + (size_t)e * EA;
      ea0 = ep[0]; ea1 = ep[1]; ea2 = ep[2];
      ea3 = ep[3]; ea4 = ep[4]; ea5 = ep[5];
    }
#define EDGE_BODY(J)                                                       \
    {                                                                      \
      int s = __shfl(s_l, (J), 64);                                        \
      float e0 = __shfl(ea0, (J), 64), e1 = __shfl(ea1, (J), 64);          \
      float e2 = __shfl(ea2, (J), 64), e3 = __shfl(ea3, (J), 64);          \
      float e4 = __shfl(ea4, (J), 64), e5 = __shfl(ea5, (J), 64);          \
      const float2 pv = *(const float2*)(P + (size_t)s * CH + c);          \
      float v0 = pv.x + q.x, v1 = pv.y + q.y;                              \
      v0 += e0 * cw[0].x; v1 += e0 * cw[0].y;                              \
      v0 += e1 * cw[1].x; v1 += e1 * cw[1].y;                              \
      v0 += e2 * cw[2].x; v1 += e2 * cw[2].y;                              \
      v0 += e3 * cw[3].x; v1 += e3 * cw[3].y;                              \
      v0 += e4 * cw[4].x; v1 += e4 * cw[4].y;                              \
      v0 += e5 * cw[5].x; v1 += e5 * cw[5].y;                              \
      if (MODE == 0) { a0 = fmaxf(a0, v0); a1 = fmaxf(a1, v1); }           \
      else           { a0 += fmaxf(v0, 0.f); a1 += fmaxf(v1, 0.f); }       \
    }
    int j = 0;
    for (; j + 8 <= cnt; j += 8) {
      EDGE_BODY(j)     EDGE_BODY(j + 1) EDGE_BODY(j + 2) EDGE_BODY(j + 3)
      EDGE_BODY(j + 4) EDGE_BODY(j + 5) EDGE_BODY(j + 6) EDGE_BODY(j + 7)
    }
    for (; j < cnt; ++j) EDGE_BODY(j)
#undef EDGE_BODY
  }
  if (MODE == 1) {
    float inv = 1.f / fmaxf((float)(i1 - i0), 1.f);
    a0 *= inv; a1 *= inv;
  }
  size_t o = (size_t)node * FUS + (size_t)cur * CH + c;
  if (prev >= 0) {
    const float2 pr = *(const float2*)(outf + (size_t)node * FUS + (size_t)prev * CH + c);
    a0 += pr.x; a1 += pr.y;
  }
  float2 ov = {a0, a1};
  *(float2*)(outf + o) = ov;
}

// ---------- convert feats -> f16, rows >= NN zero-padded ----------
__global__ __launch_bounds__(256) void k_cvtA(const float* __restrict__ feats,
                                              _Float16* __restrict__ fh) {
  const size_t off = ((size_t)blockIdx.x * 256 + threadIdx.x) * 8;
  const int row = (int)(off / FUS);
  half8 v;
  if (row < NN) {
    const float4 f0 = *(const float4*)(feats + off);
    const float4 f1 = *(const float4*)(feats + off + 4);
    v[0] = (_Float16)f0.x; v[1] = (_Float16)f0.y;
    v[2] = (_Float16)f0.z; v[3] = (_Float16)f0.w;
    v[4] = (_Float16)f1.x; v[5] = (_Float16)f1.y;
    v[6] = (_Float16)f1.z; v[7] = (_Float16)f1.w;
  } else {
#pragma unroll
    for (int j = 0; j < 8; ++j) v[j] = (_Float16)0.f;
  }
  *(half8*)(fh + off) = v;
}

// ---------- convert + pack W (KxN f32) into f16 B-fragment order ----------
// ktile c, ntile tl, lane L: elem j = W[c*32 + (L>>4)*8 + j][tl*16 + (L&15)]
template <int N, int NT>  // N = row stride (cols), NT = n-tiles = N/16
__global__ __launch_bounds__(64) void k_cvtB(const float* __restrict__ W,
                                             _Float16* __restrict__ wh) {
  const int c = blockIdx.x / NT;
  const int tile = blockIdx.x % NT;
  const int L = threadIdx.x;
  const int n = tile * 16 + (L & 15);
  const int k0 = c * 32 + (L >> 4) * 8;
  half8 v;
#pragma unroll
  for (int j = 0; j < 8; ++j) v[j] = (_Float16)W[(size_t)(k0 + j) * N + n];
  *(half8*)(wh + (((size_t)(c * NT + tile)) * 64 + L) * 8) = v;
}

// ---------- fusion GEMM on matrix cores + segment max ----------
__global__ __launch_bounds__(256) void k_pool_mfma(
    const _Float16* __restrict__ fh, const _Float16* __restrict__ wh,
    const int* __restrict__ bbox, const float* __restrict__ bf,
    float* __restrict__ pooled) {
  __shared__ float cl[64 * 128];
  const int t = threadIdx.x, lane = t & 63, wv = t >> 6;
  const int nbase = blockIdx.x * 64;
  const int cg = blockIdx.y;          // column group of 128
  const int m = lane & 15, quad = lane >> 4;
  f32x4 acc[4][2];
#pragma unroll
  for (int i = 0; i < 4; ++i)
#pragma unroll
    for (int nt = 0; nt < 2; ++nt) acc[i][nt] = (f32x4){0.f, 0.f, 0.f, 0.f};
  const _Float16* ap = fh + (size_t)(nbase + m) * FUS + quad * 8;
  const _Float16* bp = wh + ((size_t)(cg * 8 + wv * 2) * 64 + lane) * 8;
#pragma unroll
  for (int ks = 0; ks < 12; ++ks) {
    const half8 b0 = *(const half8*)(bp + (size_t)ks * 32768);
    const half8 b1 = *(const half8*)(bp + (size_t)ks * 32768 + 512);
#pragma unroll
    for (int i = 0; i < 4; ++i) {
      const half8 a = *(const half8*)(ap + (size_t)(i * 16) * FUS + ks * 32);
      acc[i][0] = __builtin_amdgcn_mfma_f32_16x16x32_f16(a, b0, acc[i][0], 0, 0, 0);
      acc[i][1] = __builtin_amdgcn_mfma_f32_16x16x32_f16(a, b1, acc[i][1], 0, 0, 0);
    }
  }
#pragma unroll
  for (int i = 0; i < 4; ++i)
#pragma unroll
    for (int nt = 0; nt < 2; ++nt) {
      const int col = wv * 32 + nt * 16 + m;
#pragma unroll
      for (int r = 0; r < 4; ++r)
        cl[(i * 16 + quad * 4 + r) * 128 + col] = acc[i][nt][r];
    }
  __syncthreads();
  if (t < 128) {
    const int gcol = cg * 128 + t;
    const float bias = bf[gcol];
    int curb = -1;
    float mx = 0.f;
    for (int row = 0; row < 64; ++row) {
      const int node = nbase + row;
      if (node >= NN) break;
      const int bid = bbox[node];
      const float v = fmaxf(cl[row * 128 + t] + bias, 0.f);
      if (bid != curb) {
        if (curb >= 0)
          atomicMax((unsigned*)(pooled + (size_t)curb * 1408 + gcol),
                    __float_as_uint(mx));
        curb = bid;
        mx = v;
      } else {
        mx = fmaxf(mx, v);
      }
    }
    if (curb >= 0)
      atomicMax((unsigned*)(pooled + (size_t)curb * 1408 + gcol),
                __float_as_uint(mx));
  }
}

// ---------- raw-feats bbox max + sfeats bbox mean ----------
__global__ __launch_bounds__(256) void k_poolraw(
    const float* __restrict__ feats, const float* __restrict__ sfeats,
    const int* __restrict__ seg, float* __restrict__ pooled,
    float* __restrict__ sb) {
  const int b = blockIdx.x, t = threadIdx.x;
  if (t >= 192) return;
  const int c2 = t * 2;
  const int n0 = __builtin_amdgcn_readfirstlane(seg[b]);
  const int n1 = __builtin_amdgcn_readfirstlane(seg[b + 1]);
  float2 fmx = {0.f, 0.f}, ss = {0.f, 0.f};
  for (int n = n0; n < n1; ++n) {
    const float2 f2 = *(const float2*)(feats + (size_t)n * FUS + c2);
    fmx.x = fmaxf(fmx.x, f2.x); fmx.y = fmaxf(fmx.y, f2.y);
    const float2 s2 = *(const float2*)(sfeats + (size_t)n * FUS + c2);
    ss.x += s2.x; ss.y += s2.y;
  }
  *(float2*)(pooled + (size_t)b * 1408 + 1024 + c2) = fmx;
  const float inv = 1.f / fmaxf((float)(n1 - n0), 1.f);
  float2 o = {ss.x * inv, ss.y * inv};
  *(float2*)(sb + (size_t)b * FUS + c2) = o;
}

// ---------- fusion_super = relu(sb @ Wfs + bfs), lane-distributed x ----------
__global__ __launch_bounds__(256) void k_fusion_super(
    const float* __restrict__ sb, const float* __restrict__ Wfs,
    const float* __restrict__ bfs, float* __restrict__ fs) {
  const int t = threadIdx.x, lane = t & 63, wv = t >> 6;
  const int r0 = blockIdx.x * 4;
  const int c = (blockIdx.y * 4 + wv) * 128 + lane * 2;
  float2 acc[4];
#pragma unroll
  for (int u = 0; u < 4; ++u) acc[u] = make_float2(0.f, 0.f);
  const int xr = r0 + (lane >> 4), xk = lane & 15;
  for (int k0 = 0; k0 < FUS; k0 += 16) {
    const float xv = sb[(size_t)xr * FUS + k0 + xk];
#pragma unroll
    for (int j = 0; j < 16; ++j) {
      const float2 w = *(const float2*)(Wfs + (size_t)(k0 + j) * 1024 + c);
#pragma unroll
      for (int u = 0; u < 4; ++u) {
        const float xs = __shfl(xv, u * 16 + j, 64);
        acc[u].x += xs * w.x; acc[u].y += xs * w.y;
      }
    }
  }
  const float2 b = *(const float2*)(bfs + c);
#pragma unroll
  for (int u = 0; u < 4; ++u) {
    float2 o = {fmaxf(acc[u].x + b.x, 0.f), fmaxf(acc[u].y + b.y, 0.f)};
    *(float2*)(fs + (size_t)(r0 + u) * 1024 + c) = o;
  }
}

// ---------- concat [pooled | fsup | sb] -> f16 bbH[NB_PAD][K1], zero-padded ----
__global__ __launch_bounds__(256) void k_cvt_cat(
    const float* __restrict__ pooled, const float* __restrict__ fsup,
    const float* __restrict__ sb, _Float16* __restrict__ bbH) {
  const size_t off = ((size_t)blockIdx.x * 256 + threadIdx.x) * 8;
  const int row = (int)(off / K1);
  const int col = (int)(off - (size_t)row * K1);   // 8-chunks never straddle seg bounds
  half8 v;
  if (row < NB) {
    const float* src;
    if (col < 1408)      src = pooled + (size_t)row * 1408 + col;
    else if (col < 2432) src = fsup + (size_t)row * 1024 + (col - 1408);
    else                 src = sb + (size_t)row * FUS + (col - 2432);
    const float4 f0 = *(const float4*)src;
    const float4 f1 = *(const float4*)(src + 4);
    v[0] = (_Float16)f0.x; v[1] = (_Float16)f0.y;
    v[2] = (_Float16)f0.z; v[3] = (_Float16)f0.w;
    v[4] = (_Float16)f1.x; v[5] = (_Float16)f1.y;
    v[6] = (_Float16)f1.z; v[7] = (_Float16)f1.w;
  } else {
#pragma unroll
    for (int j = 0; j < 8; ++j) v[j] = (_Float16)0.f;
  }
  *(half8*)(bbH + off) = v;
}

// ---------- h1 = relu(bbH @ W1 + b1) on matrix cores ----------
// Block 64 rows x 128 cols; grid (NB_PAD/64=32, 512/128=4). K=2816 = 88 ktiles.
__global__ __launch_bounds__(256) void k_mlp1_mfma(
    const _Float16* __restrict__ bbH, const _Float16* __restrict__ wh,
    const float* __restrict__ b1, float* __restrict__ h1) {
  const int t = threadIdx.x, lane = t & 63, wv = t >> 6;
  const int nbase = blockIdx.x * 64;
  const int cg = blockIdx.y;
  const int m = lane & 15, quad = lane >> 4;
  f32x4 acc[4][2];
#pragma unroll
  for (int i = 0; i < 4; ++i)
#pragma unroll
    for (int nt = 0; nt < 2; ++nt) acc[i][nt] = (f32x4){0.f, 0.f, 0.f, 0.f};
  const _Float16* ap = bbH + (size_t)(nbase + m) * K1 + quad * 8;
  const _Float16* bp = wh + ((size_t)(cg * 8 + wv * 2) * 64 + lane) * 8;
#pragma unroll 4
  for (int ks = 0; ks < 88; ++ks) {
    const half8 b0 = *(const half8*)(bp + (size_t)ks * 16384);
    const half8 b1v = *(const half8*)(bp + (size_t)ks * 16384 + 512);
#pragma unroll
    for (int i = 0; i < 4; ++i) {
      const half8 a = *(const half8*)(ap + (size_t)(i * 16) * K1 + ks * 32);
      acc[i][0] = __builtin_amdgcn_mfma_f32_16x16x32_f16(a, b0, acc[i][0], 0, 0, 0);
      acc[i][1] = __builtin_amdgcn_mfma_f32_16x16x32_f16(a, b1v, acc[i][1], 0, 0, 0);
    }
  }
#pragma unroll
  for (int i = 0; i < 4; ++i)
#pragma unroll
    for (int nt = 0; nt < 2; ++nt) {
      const int gcol = cg * 128 + wv * 32 + nt * 16 + m;
      const float bias = b1[gcol];
#pragma unroll
      for (int r = 0; r < 4; ++r) {
        const int row = nbase + i * 16 + quad * 4 + r;
        if (row < NB)
          h1[(size_t)row * 512 + gcol] = fmaxf(acc[i][nt][r] + bias, 0.f);
      }
    }
}

// ---------- h2 = relu(h1 @ W2 + b2) ----------
__global__ __launch_bounds__(256) void k_mlp2(
    const float* __restrict__ h1, const float* __restrict__ W2,
    const float* __restrict__ b2, float* __restrict__ h2) {
  const int r0 = blockIdx.x * 8, t = threadIdx.x;
  float acc[8];
#pragma unroll
  for (int u = 0; u < 8; ++u) acc[u] = 0.f;
  for (int k = 0; k < 512; ++k) {
    float w = W2[(size_t)k * 256 + t];
#pragma unroll
    for (int u = 0; u < 8; ++u) acc[u] += h1[(size_t)(r0 + u) * 512 + k] * w;
  }
  float bv = b2[t];
#pragma unroll
  for (int u = 0; u < 8; ++u)
    h2[(size_t)(r0 + u) * 256 + t] = fmaxf(acc[u] + bv, 0.f);
}

// ---------- logits = h2 @ W3 + b3 ----------
__global__ __launch_bounds__(256) void k_mlp3(
    const float* __restrict__ h2, const float* __restrict__ W3,
    const float* __restrict__ b3, float* __restrict__ out) {
  const int r0 = blockIdx.x * 8, t = threadIdx.x;
  const int u = t >> 5, oc = t & 31;
  const float* x = h2 + (size_t)(r0 + u) * 256;
  float acc = 0.f;
  for (int k = 0; k < 256; ++k) acc += x[k] * W3[(size_t)k * 32 + oc];
  out[(size_t)(r0 + u) * 32 + oc] = acc + b3[oc];
}

extern "C" void kernel_launch(void* const* d_in, const int* in_sizes, int n_in,
                              void* d_out, int out_size, void* d_ws, size_t ws_size,
                              hipStream_t stream) {
  const float* x     = (const float*)d_in[0];
  const float* eattr = (const float*)d_in[1];
  const float* W_h   = (const float*)d_in[2];
  const float* b_h   = (const float*)d_in[3];
  const float* Ws_h  = (const float*)d_in[4];
  const float* bs_h  = (const float*)d_in[5];
  const float* Wb    = (const float*)d_in[6];
  const float* bb    = (const float*)d_in[7];
  const float* Wbs   = (const float*)d_in[8];
  const float* bbs   = (const float*)d_in[9];
  const float* W_f   = (const float*)d_in[10];
  const float* b_f   = (const float*)d_in[11];
  const float* W_fs  = (const float*)d_in[12];
  const float* b_fs  = (const float*)d_in[13];
  const float* W1    = (const float*)d_in[14];
  const float* b1    = (const float*)d_in[15];
  const float* W2    = (const float*)d_in[16];
  const float* b2    = (const float*)d_in[17];
  const float* W3    = (const float*)d_in[18];
  const float* b3    = (const float*)d_in[19];
  const int*   edge  = (const int*)d_in[20];
  const int*   bbox  = (const int*)d_in[21];
  float* out = (float*)d_out;

  // ---- workspace layout (~209 MB, unchanged footprint) ----
  float* p = (float*)d_ws;
  float* feats  = p; p += (size_t)NN * FUS;       // 76.8 MB
  float* sfeats = p; p += (size_t)NN * FUS;       // 76.8 MB
  float* PQ     = p; p += (size_t)2 * NN * CH;    // 51.2 MB = 12.8M floats
  float* P = PQ;
  float* Q = PQ + (size_t)NN * CH;
  // overlays inside PQ (live only AFTER the last k_conv):
  _Float16* featsH = (_Float16*)PQ;                         // 9.609M floats
  _Float16* WfH    = featsH + (size_t)NN_PAD * FUS;         // 0.197M floats
  float* pooled    = (float*)(WfH + (size_t)FUS * 1024);    // 2.816M floats
  //   total: 12.62M <= 12.8M. After k_pool_mfma, featsH region reused:
  float* sb   = PQ;                                         // 0.768M
  float* fsup = sb + (size_t)NB * FUS;                      // 2.048M
  float* h1   = fsup + (size_t)NB * 1024;                   // 1.024M
  float* h2   = h1 + (size_t)NB * 512;                      // 0.512M  (tot 4.352M)
  _Float16* bbH = (_Float16*)(h2 + (size_t)NB * 256);       // 2.884M floats
  _Float16* W1H = bbH + (size_t)NB_PAD * K1;                // 0.721M floats
  //   4.352 + 2.884 + 0.721 = 7.957M <= 9.606M (pooled starts at 9.806M). ok
  int* eid_arr = (int*)p;
  int* row_ptr = eid_arr + NE;
  int* deg     = row_ptr + NN + 1;
  int* cursor  = deg + NN;
  int* seg     = cursor + NN;

  hipMemsetAsync(deg, 0, 2 * NN * sizeof(int), stream);  // deg + cursor

  // ---- CSR build + bbox segments ----
  k_deg<<<(NE + 255) / 256, 256, 0, stream>>>(edge, deg);
  k_scan<<<1, 1024, 0, stream>>>(deg, row_ptr);
  k_fill<<<(NE + 255) / 256, 256, 0, stream>>>(edge, row_ptr, cursor, eid_arr);
  k_segstart<<<(NN + 255) / 256, 256, 0, stream>>>(bbox, seg);

  const int npq_grid = (NN + 31) / 32;

  // ---- conv 0 (head): both streams read x (K=8) ----
  k_node_pq<<<npq_grid, 256, 0, stream>>>(x, INCH, INCH, W_h, b_h, P, Q);
  k_conv<0><<<NN / 4, 256, 0, stream>>>(row_ptr, eid_arr, edge, eattr, P, Q,
                                        W_h + 2 * INCH * CH, feats, 0, -1);
  k_node_pq<<<npq_grid, 256, 0, stream>>>(x, INCH, INCH, Ws_h, bs_h, P, Q);
  k_conv<1><<<NN / 4, 256, 0, stream>>>(row_ptr, eid_arr, edge, eattr, P, Q,
                                        Ws_h + 2 * INCH * CH, sfeats, 0, -1);

  // ---- residual blocks (K=128) ----
  for (int i = 0; i < 2; ++i) {
    const float* Wi  = Wb  + (size_t)i * 262 * CH;
    const float* bi  = bb  + (size_t)i * CH;
    const float* Wsi = Wbs + (size_t)i * 262 * CH;
    const float* bsi = bbs + (size_t)i * CH;
    k_node_pq<<<npq_grid, 256, 0, stream>>>(feats + i * CH, FUS, CH, Wi, bi, P, Q);
    k_conv<0><<<NN / 4, 256, 0, stream>>>(row_ptr, eid_arr, edge, eattr, P, Q,
                                          Wi + 2 * CH * CH, feats, i + 1, i);
    k_node_pq<<<npq_grid, 256, 0, stream>>>(sfeats + i * CH, FUS, CH, Wsi, bsi, P, Q);
    k_conv<1><<<NN / 4, 256, 0, stream>>>(row_ptr, eid_arr, edge, eattr, P, Q,
                                          Wsi + 2 * CH * CH, sfeats, i + 1, i);
  }

  // ---- pooling: f16 converts + MFMA GEMM + atomicMax epilogue ----
  k_cvtA<<<(int)(((size_t)NN_PAD * FUS / 8) / 256), 256, 0, stream>>>(feats, featsH);
  k_cvtB<1024, 64><<<12 * 64, 64, 0, stream>>>(W_f, WfH);
  hipMemsetAsync(pooled, 0, (size_t)NB * 1408 * sizeof(float), stream);
  k_pool_mfma<<<dim3(NN_PAD / 64, 8), 256, 0, stream>>>(featsH, WfH, bbox, b_f,
                                                        pooled);
  k_poolraw<<<NB, 256, 0, stream>>>(feats, sfeats, seg, pooled, sb);
  k_fusion_super<<<dim3(NB / 4, 2), 256, 0, stream>>>(sb, W_fs, b_fs, fsup);

  // ---- head MLP: concat->f16, W1->f16 frag, MFMA GEMM, then small MLPs ----
  k_cvt_cat<<<(int)(((size_t)NB_PAD * K1 / 8) / 256), 256, 0, stream>>>(
      pooled, fsup, sb, bbH);
  k_cvtB<512, 32><<<88 * 32, 64, 0, stream>>>(W1, W1H);
  k_mlp1_mfma<<<dim3(NB_PAD / 64, 4), 256, 0, stream>>>(bbH, W1H, b1, h1);
  k_mlp2<<<NB / 8, 256, 0, stream>>>(h1, W2, b2, h2);
  k_mlp3<<<NB / 8, 256, 0, stream>>>(h2, W3, b3, out);
}